// Round 1
// baseline (33300.723 us; speedup 1.0000x reference)
//
#include <hip/hip_runtime.h>
#include <math.h>

// Problem dims (fixed by the reference)
#define BB 64
#define TT 1024
#define EE 256
#define HH 512
#define OO 32000
#define KDIM 768   // H+E

typedef float f32x2 __attribute__((ext_vector_type(2)));

__device__ __forceinline__ f32x2 mk2(float a, float b) { f32x2 r; r.x = a; r.y = b; return r; }

#if __has_builtin(__builtin_elementwise_fma)
#define FMA2(a, b, c) __builtin_elementwise_fma((a), (b), (c))
#else
__device__ __forceinline__ f32x2 FMA2(f32x2 a, f32x2 b, f32x2 c) {
  c.x = fmaf(a.x, b.x, c.x); c.y = fmaf(a.y, b.y, c.y); return c;
}
#endif

// ---------------------------------------------------------------------------
// Recurrence kernel: one block per batch element, 1024 threads (16 waves).
// Thread tid = kg*64 + jl:
//   kg = wave index 0..15  -> owns k-range [kg*48, kg*48+48)  of combined [h;e]
//   jl = lane  index 0..63 -> owns j-range [jl*8,  jl*8+8)    of hidden outputs
// Weights (8 j x 48 k = 384 f32) live in registers for the whole T loop.
// All 64 lanes of a wave read the SAME combined[k] slice -> LDS broadcast,
// conflict-free. Partials reduced across the 16 waves through LDS.
// ---------------------------------------------------------------------------
__global__ __launch_bounds__(1024) void rnn_kernel(
    const int* __restrict__ x, const float* __restrict__ hidden0,
    const float* __restrict__ emb, const float* __restrict__ Wi,
    const float* __restrict__ bi, float* __restrict__ hid_out)
{
  __shared__ float4 comb4[KDIM / 4];       // [0..127] = h, [128..191] = e
  __shared__ float4 part4[16 * HH / 4];    // part[16][512]
  __shared__ int xrow[TT];
  float* comb = (float*)comb4;
  float* part = (float*)part4;

  const int b   = blockIdx.x;
  const int tid = threadIdx.x;
  const int kg  = tid >> 6;
  const int jl  = tid & 63;

  // init: x row into LDS, h(0) into comb
  xrow[tid] = x[b * TT + tid];
  if (tid < HH) comb[tid] = hidden0[b * HH + tid];
  __syncthreads();

  const float4* emb4 = (const float4*)emb;
  // e(0) (padding_idx = 0 -> zeros)
  if (kg == 8) {
    int idx = xrow[0];
    float4 e0 = make_float4(0.f, 0.f, 0.f, 0.f);
    if (idx != 0) e0 = emb4[idx * (EE / 4) + jl];
    comb4[HH / 4 + jl] = e0;
  }

  // preload this thread's weight tile into registers: w2[jj][pair over 48 k]
  f32x2 w2[8][24];
  {
    const float4* Wi4 = (const float4*)Wi;
    #pragma unroll
    for (int jj = 0; jj < 8; ++jj) {
      const int row = jl * 8 + jj;
      const float4* wr = Wi4 + (row * KDIM + kg * 48) / 4;
      #pragma unroll
      for (int q = 0; q < 12; ++q) {
        float4 v = wr[q];
        w2[jj][q * 2 + 0] = mk2(v.x, v.y);
        w2[jj][q * 2 + 1] = mk2(v.z, v.w);
      }
    }
  }
  const float bj = (tid < HH) ? bi[tid] : 0.0f;
  __syncthreads();

  #pragma unroll 1
  for (int t = 0; t < TT; ++t) {
    // ---------------- phase 1: dot-products + e(t+1) prefetch ----------------
    float4 e4 = make_float4(0.f, 0.f, 0.f, 0.f);
    if (kg == 8 && t + 1 < TT) {
      int idx = xrow[t + 1];
      if (idx != 0) e4 = emb4[idx * (EE / 4) + jl];   // latency hidden under FMAs
    }

    f32x2 acc[8];
    #pragma unroll
    for (int jj = 0; jj < 8; ++jj) acc[jj] = mk2(0.f, 0.f);

    const float4* c4 = comb4 + kg * 12;   // this wave's 48-float slice (broadcast)
    #pragma unroll
    for (int c = 0; c < 4; ++c) {
      float4 h0 = c4[c * 3 + 0];
      float4 h1 = c4[c * 3 + 1];
      float4 h2 = c4[c * 3 + 2];
      f32x2 hh0 = mk2(h0.x, h0.y), hh1 = mk2(h0.z, h0.w);
      f32x2 hh2 = mk2(h1.x, h1.y), hh3 = mk2(h1.z, h1.w);
      f32x2 hh4 = mk2(h2.x, h2.y), hh5 = mk2(h2.z, h2.w);
      #pragma unroll
      for (int jj = 0; jj < 8; ++jj) {
        acc[jj] = FMA2(w2[jj][c * 6 + 0], hh0, acc[jj]);
        acc[jj] = FMA2(w2[jj][c * 6 + 1], hh1, acc[jj]);
        acc[jj] = FMA2(w2[jj][c * 6 + 2], hh2, acc[jj]);
        acc[jj] = FMA2(w2[jj][c * 6 + 3], hh3, acc[jj]);
        acc[jj] = FMA2(w2[jj][c * 6 + 4], hh4, acc[jj]);
        acc[jj] = FMA2(w2[jj][c * 6 + 5], hh5, acc[jj]);
      }
    }

    // write 8 partial sums (two float4 stores) into part[kg][jl*8 .. jl*8+7]
    float4 p0 = make_float4(acc[0].x + acc[0].y, acc[1].x + acc[1].y,
                            acc[2].x + acc[2].y, acc[3].x + acc[3].y);
    float4 p1 = make_float4(acc[4].x + acc[4].y, acc[5].x + acc[5].y,
                            acc[6].x + acc[6].y, acc[7].x + acc[7].y);
    part4[kg * 128 + jl * 2 + 0] = p0;
    part4[kg * 128 + jl * 2 + 1] = p1;
    __syncthreads();

    // ---------------- phase 2: reduce across waves, tanh, update comb -------
    if (tid < HH) {
      float s = bj;
      #pragma unroll
      for (int g = 0; g < 16; ++g) s += part[g * HH + tid];
      comb[tid] = tanhf(s);
    }
    if (kg == 8 && t + 1 < TT) comb4[HH / 4 + jl] = e4;
    __syncthreads();
  }

  if (tid < HH) hid_out[b * HH + tid] = comb[tid];
}

// ---------------------------------------------------------------------------
// Decoder: out[b][o] = sum_j h[b][j] * W_dec[o][j] + b_dec[o]
// grid (125, 2): 256 o-columns per block, 32 batch rows per block.
// h tile staged in LDS [32][512] f32 (64 KB), read as float4 broadcasts.
// ---------------------------------------------------------------------------
__global__ __launch_bounds__(256) void dec_kernel(
    const float* __restrict__ hid, const float* __restrict__ Wd,
    const float* __restrict__ bd, float* __restrict__ out)
{
  __shared__ float4 hl4[32 * 128];   // [bb][j4] — contiguous copy of hid[b0..b0+32)
  const int o  = blockIdx.x * 256 + threadIdx.x;
  const int b0 = blockIdx.y * 32;

  const float4* hid4 = (const float4*)(hid + b0 * HH);
  #pragma unroll
  for (int i = 0; i < 16; ++i) {
    int lin = i * 256 + threadIdx.x;
    hl4[lin] = hid4[lin];
  }
  __syncthreads();

  f32x2 acc[32];
  #pragma unroll
  for (int bb = 0; bb < 32; ++bb) acc[bb] = mk2(0.f, 0.f);

  const float4* W4 = (const float4*)(Wd + (size_t)o * HH);
  for (int j4 = 0; j4 < 128; ++j4) {
    float4 w = W4[j4];
    f32x2 wa = mk2(w.x, w.y), wb = mk2(w.z, w.w);
    #pragma unroll
    for (int bb = 0; bb < 32; ++bb) {
      float4 h = hl4[bb * 128 + j4];
      acc[bb] = FMA2(wa, mk2(h.x, h.y), acc[bb]);
      acc[bb] = FMA2(wb, mk2(h.z, h.w), acc[bb]);
    }
  }

  const float bias = bd[o];
  #pragma unroll
  for (int bb = 0; bb < 32; ++bb)
    out[(size_t)(b0 + bb) * OO + o] = acc[bb].x + acc[bb].y + bias;
}

// ---------------------------------------------------------------------------
extern "C" void kernel_launch(void* const* d_in, const int* in_sizes, int n_in,
                              void* d_out, int out_size, void* d_ws, size_t ws_size,
                              hipStream_t stream) {
  const int*   x    = (const int*)  d_in[0];   // [64][1024] int32
  const float* hid0 = (const float*)d_in[1];   // [64][512]
  const float* emb  = (const float*)d_in[2];   // [32000][256]
  const float* Wi   = (const float*)d_in[3];   // [512][768]
  const float* bi   = (const float*)d_in[4];   // [512]
  const float* Wd   = (const float*)d_in[5];   // [32000][512]
  const float* bd   = (const float*)d_in[6];   // [32000]

  float* out     = (float*)d_out;              // [64][32000] output
  float* hid_out = out + (size_t)BB * OO;      // [64][512] final hidden

  rnn_kernel<<<BB, 1024, 0, stream>>>(x, hid0, emb, Wi, bi, hid_out);
  dec_kernel<<<dim3(OO / 256, BB / 32), 256, 0, stream>>>(hid_out, Wd, bd, out);
}